// Round 21
// baseline (1483.984 us; speedup 1.0000x reference)
//
#include <hip/hip_runtime.h>
#include <hip/hip_bf16.h>
#include <stdint.h>

typedef __attribute__((ext_vector_type(8))) short short8;
typedef __attribute__((ext_vector_type(4))) float f32x4;
typedef unsigned short bfu;

#define T_TILE  32
#define RING    256            // ring rows (pow2): live span/tile = 64+d <= 192 < 256
#define NLAYERS 16
#define T0LEN   131072
#define BATCH   8
#define RFIELD  510            // sum of dilations
#define FINLEN  130560         // 510 pool windows * 256
#define CHCAP   65280          // chunk cap: 2x bf16 buffers (~135MB) stay L3-resident

// barrier WITHOUT vmcnt drain: safe (no cross-wave GLOBAL communication inside
// a layer kernel; only LDS visibility needed). Global loads stay in flight.
#define BARRIER() asm volatile("s_waitcnt lgkmcnt(0)\n\ts_barrier" ::: "memory")

__device__ __forceinline__ bfu f2bf(float f) {
    unsigned u = __float_as_uint(f);
    u += 0x7FFFu + ((u >> 16) & 1u);      // RNE (cold prep kernel only)
    return (bfu)(u >> 16);
}
__device__ __forceinline__ unsigned pk2(float a, float b) {
    __hip_bfloat16 lo = __float2bfloat16(a);
    __hip_bfloat16 hi = __float2bfloat16(b);
    unsigned short ul = __builtin_bit_cast(unsigned short, lo);
    unsigned short uh = __builtin_bit_cast(unsigned short, hi);
    return (unsigned)ul | ((unsigned)uh << 16);
}
__device__ __forceinline__ float bf2f(bfu h) { return __uint_as_float(((unsigned)h) << 16); }
__device__ __forceinline__ unsigned relu2(unsigned w) {
    return w & ~(((w >> 15) & 0x00010001u) * 0xFFFFu);
}

// ---- weights: Wd[l][o][c][tap] -> wcat[l][o][k] bf16 (k=tap*64+c); Wr -> wrb bf16
__global__ void prep_weights(const float* __restrict__ Wd, const float* __restrict__ Wr,
                             bfu* __restrict__ wcat, bfu* __restrict__ wrb)
{
    int idx = blockIdx.x * 256 + threadIdx.x;
    const int total1 = NLAYERS * 128 * 128;
    if (idx < total1) {
        int k = idx & 127, o = (idx >> 7) & 127, l = idx >> 14;
        int tap = k >> 6, c = k & 63;
        wcat[idx] = f2bf(Wd[(((l * 128 + o) * 64) + c) * 2 + tap]);
    } else {
        int j = idx - total1;
        if (j < NLAYERS * 64 * 128) wrb[j] = f2bf(Wr[j]);
    }
}

// MODE: 0 = middle, 1 = first (input conv fused; d==1), 2 = last (final conv+pool fused)
// T_TILE=32 variant: rx ring 256 rows (32KB) + hb 32x128 (8KB) = 40KB -> 4 blocks/CU
// (160KB LDS exactly). Same structure as the 1471us r20 kernel otherwise.
template <int MODE>
__global__ __launch_bounds__(256, 4)
void layer_kernel(const bfu* __restrict__ xin, bfu* __restrict__ xout,
                  const bfu* __restrict__ wcat, const bfu* __restrict__ wrb,
                  const float* __restrict__ bd, const float* __restrict__ br,
                  const float* __restrict__ sig, const float* __restrict__ W0,
                  const float* __restrict__ b0, const float* __restrict__ Wf,
                  float* __restrict__ partial,
                  int s, int d, int Lin, int Lout, int Rrows, int NT, int tiles)
{
    __shared__ bfu rx[RING * 64];      // 32 KB ring: relu(x) bf16, swizzled rows
    __shared__ bfu hb[32 * 128];       // 8 KB: relu(h+bd) bf16, swizzled

    const int tid  = threadIdx.x;
    const int lane = tid & 63;
    const int wv   = tid >> 6;
    const int l15  = lane & 15;
    const int lg   = lane >> 4;
    const int b    = blockIdx.y;

    const bfu* xb = xin  + (long)b * Rrows * 64;
    bfu*       xo = xout + (long)b * Rrows * 64;
    const float* sgb = sig + (long)b * T0LEN + s;

    // ---- loop-invariant: weight A-fragments, biases ----
    short8 a1[2][4];
    #pragma unroll
    for (int m = 0; m < 2; ++m)
        #pragma unroll
        for (int k = 0; k < 4; ++k)
            a1[m][k] = *(const short8*)(wcat + ((wv * 32 + m * 16 + l15) << 7) + (k << 5) + (lg << 3));
    short8 a2[4];
    #pragma unroll
    for (int k = 0; k < 4; ++k)
        a2[k] = *(const short8*)(wrb + ((wv * 16 + l15) << 7) + (k << 5) + (lg << 3));

    const int c0 = wv * 16 + lg * 4;
    const f32x4 brv = *(const f32x4*)(br + c0);
    f32x4 bd4[2];
    #pragma unroll
    for (int m = 0; m < 2; ++m)
        bd4[m] = *(const f32x4*)(bd + wv * 32 + m * 16 + lg * 4);
    f32x4 wfv;
    if constexpr (MODE == 2) wfv = *(const f32x4*)(Wf + c0);

    const int tile0 = blockIdx.x * NT;
    const int jmax  = (tiles - tile0 < NT) ? (tiles - tile0) : NT;
    if (jmax <= 0) return;
    const int t00   = tile0 * T_TILE;

    // ---- prologue: stage rows [t00, t00+T_TILE+d) into ring ----
    if constexpr (MODE == 1) {
        const int nsl = (T_TILE + 1) * 8;            // d == 1 -> 264
        #pragma unroll
        for (int it = 0; it < 2; ++it) {
            int i = tid + it * 256;
            if (i < nsl) {
                int r = i >> 3, oc = i & 7;
                int t = t00 + r; if (t > Lin - 1) t = Lin - 1;
                float sv = sgb[t];
                unsigned pk[4];
                #pragma unroll
                for (int kk = 0; kk < 4; ++kk) {
                    int c = oc * 8 + kk * 2;
                    pk[kk] = pk2(fmaxf(W0[c] * sv + b0[c], 0.f),
                                 fmaxf(W0[c + 1] * sv + b0[c + 1], 0.f));
                }
                int rs = (t00 + r) & (RING - 1);
                uint4 u; u.x = pk[0]; u.y = pk[1]; u.z = pk[2]; u.w = pk[3];
                *(uint4*)&rx[(rs << 6) + ((oc ^ (rs & 7)) << 3)] = u;
            }
        }
    } else {
        const int nsl = (T_TILE + d) * 8;            // <= 1280
        uint4 pv[5];
        #pragma unroll
        for (int it = 0; it < 5; ++it) {             // batch-issue all loads
            int i = tid + it * 256;
            if (i < nsl) {
                int r = i >> 3, oc = i & 7;
                long t = t00 + r; if (t > Lin - 1) t = Lin - 1;
                pv[it] = *(const uint4*)(xb + t * 64 + oc * 8);
            }
        }
        #pragma unroll
        for (int it = 0; it < 5; ++it) {             // then all writes
            int i = tid + it * 256;
            if (i < nsl) {
                int r = i >> 3, oc = i & 7;
                int rs = (t00 + r) & (RING - 1);
                uint4 v = pv[it];
                v.x = relu2(v.x); v.y = relu2(v.y); v.z = relu2(v.z); v.w = relu2(v.w);
                *(uint4*)&rx[(rs << 6) + ((oc ^ (rs & 7)) << 3)] = v;
            }
        }
    }

    for (int j = 0; j < jmax; ++j) {
        const int t0    = t00 + j * T_TILE;
        const int base0 = t0 & (RING - 1);
        const int rbase = t0 + T_TILE + d;           // first new row for tile j+1

        BARRIER();   // top: all waves done with prev GEMM2 (hb free); ring stage visible

        // ---- issue prefetch of tile j+1's 32 new rows (in flight through GEMM1) ----
        // no-wrap proof: live span = [t0, rbase+31] = 64+d <= 192 < RING; prefetch
        // slots (t0+32+d .. t0+63+d) disjoint from reader rows (t0 .. t0+31+d).
        uint4 pf;
        float pfs;
        const bool havePF = (j + 1 < jmax);
        if (havePF) {
            if constexpr (MODE == 1) {
                int t = rbase + (tid >> 3); if (t > Lin - 1) t = Lin - 1;
                pfs = sgb[t];
            } else {
                int oc = tid & 7;
                long t = rbase + (tid >> 3); if (t > Lin - 1) t = Lin - 1;
                pf = *(const uint4*)(xb + t * 64 + oc * 8);
            }
        }

        // ---- issue skip loads for this tile (consumed at epilogue 2) ----
        uint2 sk[2];
        float skv[2];
        if constexpr (MODE == 1) {
            #pragma unroll
            for (int n = 0; n < 2; ++n) {
                int t = t0 + n * 16 + l15;
                skv[n] = (t < Lout) ? sgb[t + d] : 0.f;
            }
        } else {
            #pragma unroll
            for (int n = 0; n < 2; ++n) {
                int t = t0 + n * 16 + l15;
                uint2 z = {0u, 0u};
                sk[n] = (t < Lout) ? *(const uint2*)(xb + (long)(t + d) * 64 + c0) : z;
            }
        }

        // ---- GEMM1: H[o][t] = bd[o] + sum_k Wcat[o][k] * RX[k][t] ----
        f32x4 acc[2][2];
        #pragma unroll
        for (int m = 0; m < 2; ++m)
            #pragma unroll
            for (int n = 0; n < 2; ++n) acc[m][n] = bd4[m];
        __builtin_amdgcn_s_setprio(1);
        #pragma unroll
        for (int k = 0; k < 4; ++k) {
            const int roff = (k >> 1) ? d : 0;
            const int g    = ((k & 1) << 2) + lg;
            #pragma unroll
            for (int n = 0; n < 2; ++n) {
                int rr = (base0 + n * 16 + l15 + roff) & (RING - 1);
                short8 bv = *(const short8*)&rx[(rr << 6) + ((g ^ (rr & 7)) << 3)];
                acc[0][n] = __builtin_amdgcn_mfma_f32_16x16x32_bf16(a1[0][k], bv, acc[0][n], 0, 0, 0);
                acc[1][n] = __builtin_amdgcn_mfma_f32_16x16x32_bf16(a1[1][k], bv, acc[1][n], 0, 0, 0);
            }
        }
        __builtin_amdgcn_s_setprio(0);

        // ---- epilogue 1: relu, bf16 -> hb swizzled ----
        #pragma unroll
        for (int m = 0; m < 2; ++m) {
            const int o0 = wv * 32 + m * 16 + lg * 4;
            const int gg = o0 >> 3;
            #pragma unroll
            for (int n = 0; n < 2; ++n) {
                int t = n * 16 + l15;
                f32x4 h = acc[m][n];
                unsigned q01 = pk2(fmaxf(h.x, 0.f), fmaxf(h.y, 0.f));
                unsigned q23 = pk2(fmaxf(h.z, 0.f), fmaxf(h.w, 0.f));
                int idx = (t << 7) + (((gg ^ (t & 15)) << 3) | (o0 & 7));
                uint2 pk; pk.x = q01; pk.y = q23;
                *(uint2*)&hb[idx] = pk;
            }
        }

        // ---- write prefetched rows into ring (slots disjoint from tile j readers) ----
        if (havePF) {
            if constexpr (MODE == 1) {
                int r = tid >> 3, oc = tid & 7;
                float sv = pfs;
                unsigned pk[4];
                #pragma unroll
                for (int kk = 0; kk < 4; ++kk) {
                    int c = oc * 8 + kk * 2;
                    pk[kk] = pk2(fmaxf(W0[c] * sv + b0[c], 0.f),
                                 fmaxf(W0[c + 1] * sv + b0[c + 1], 0.f));
                }
                int rs = (rbase + r) & (RING - 1);
                uint4 u; u.x = pk[0]; u.y = pk[1]; u.z = pk[2]; u.w = pk[3];
                *(uint4*)&rx[(rs << 6) + ((oc ^ (rs & 7)) << 3)] = u;
            } else {
                int r = tid >> 3, oc = tid & 7;
                int rs = (rbase + r) & (RING - 1);
                uint4 v = pf;
                v.x = relu2(v.x); v.y = relu2(v.y); v.z = relu2(v.z); v.w = relu2(v.w);
                *(uint4*)&rx[(rs << 6) + ((oc ^ (rs & 7)) << 3)] = v;
            }
        }

        BARRIER();   // mid: hb visible; ring writes drained for next top-barrier

        // ---- GEMM2: Y[r][t] = br[r] + sum_o Wr[r][o] * Hb[o][t] ----
        f32x4 acc2[2];
        #pragma unroll
        for (int n = 0; n < 2; ++n) acc2[n] = brv;
        __builtin_amdgcn_s_setprio(1);
        #pragma unroll
        for (int k = 0; k < 4; ++k) {
            const int g = (k << 2) + lg;
            #pragma unroll
            for (int n = 0; n < 2; ++n) {
                int t = n * 16 + l15;
                short8 bfm = *(const short8*)&hb[(t << 7) + ((g ^ (t & 15)) << 3)];
                acc2[n] = __builtin_amdgcn_mfma_f32_16x16x32_bf16(a2[k], bfm, acc2[n], 0, 0, 0);
            }
        }
        __builtin_amdgcn_s_setprio(0);

        // ---- epilogue 2: +skip; store bf16 or fused Wf-dot partial ----
        float psum = 0.f;
        #pragma unroll
        for (int n = 0; n < 2; ++n) {
            int t = t0 + n * 16 + l15;
            if (t < Lout) {
                float s0, s1, s2, s3;
                if constexpr (MODE == 1) {
                    float sv = skv[n];
                    s0 = W0[c0] * sv + b0[c0];         s1 = W0[c0 + 1] * sv + b0[c0 + 1];
                    s2 = W0[c0 + 2] * sv + b0[c0 + 2]; s3 = W0[c0 + 3] * sv + b0[c0 + 3];
                } else {
                    s0 = bf2f((bfu)(sk[n].x & 0xFFFF)); s1 = bf2f((bfu)(sk[n].x >> 16));
                    s2 = bf2f((bfu)(sk[n].y & 0xFFFF)); s3 = bf2f((bfu)(sk[n].y >> 16));
                }
                float y0 = acc2[n].x + s0;
                float y1 = acc2[n].y + s1;
                float y2 = acc2[n].z + s2;
                float y3 = acc2[n].w + s3;
                if constexpr (MODE == 2) {
                    psum += wfv.x * y0 + wfv.y * y1 + wfv.z * y2 + wfv.w * y3;
                } else {
                    uint2 pk;
                    pk.x = pk2(y0, y1);
                    pk.y = pk2(y2, y3);
                    *(uint2*)(xo + (long)t * 64 + c0) = pk;
                }
            }
        }
        if constexpr (MODE == 2) {
            #pragma unroll
            for (int off = 32; off > 0; off >>= 1) psum += __shfl_down(psum, off, 64);
            if (lane == 0)
                partial[((long)b * 4096 + ((s + t0) >> 5)) * 4 + wv] = psum;   // per-32-tile
        }
    }
}

// ---- final: out[b][w] = (sum of 32 partials: 8 tiles x 4 waves)/256 + bf ----
__global__ void pool_reduce(const float* __restrict__ part, const float* __restrict__ bfp,
                            float* __restrict__ out)
{
    int i = blockIdx.x * 256 + threadIdx.x;
    if (i >= BATCH * 510) return;
    int b = i / 510, w = i % 510;
    const float* p = part + ((long)b * 4096 + 8 * w) * 4;
    float sum = 0.f;
    #pragma unroll
    for (int q = 0; q < 32; ++q) sum += p[q];
    out[i] = sum * (1.0f / 256.0f) + bfp[0];
}

extern "C" void kernel_launch(void* const* d_in, const int* in_sizes, int n_in,
                              void* d_out, int out_size, void* d_ws, size_t ws_size,
                              hipStream_t stream) {
    const float* sig = (const float*)d_in[0];
    const float* W0  = (const float*)d_in[1];
    const float* b0  = (const float*)d_in[2];
    const float* Wd  = (const float*)d_in[3];
    const float* bd  = (const float*)d_in[4];
    const float* Wr  = (const float*)d_in[5];
    const float* br  = (const float*)d_in[6];
    const float* Wf  = (const float*)d_in[7];
    const float* bf  = (const float*)d_in[8];
    float* out = (float*)d_out;

    // ---- workspace: [wcat | wrb | partial | xA | xB] ----
    char* ws = (char*)d_ws;
    const size_t WCAT_E = (size_t)NLAYERS * 128 * 128;
    const size_t WRB_E  = (size_t)NLAYERS * 64 * 128;
    const size_t WBYTES = (WCAT_E + WRB_E) * 2;          // 786432
    const size_t PARTB  = (size_t)BATCH * 4096 * 4 * 4;  // 524288
    bfu*   wcat    = (bfu*)ws;
    bfu*   wrb     = (bfu*)(ws + WCAT_E * 2);
    float* partial = (float*)(ws + WBYTES);

    if (ws_size < WBYTES + PARTB + (size_t)2 * BATCH * 766 * 64 * 2) return;

    size_t avail   = ws_size - WBYTES - PARTB;
    long   rowsMax = (long)(avail / ((size_t)2 * BATCH * 64 * 2));
    long   CH      = ((rowsMax - RFIELD) / 256) * 256;
    if (CH > CHCAP) CH = CHCAP;        // L3 blocking
    if (CH < 256)   CH = 256;
    const long Rrows = CH + RFIELD;

    bfu* xA = (bfu*)(ws + WBYTES + PARTB);
    bfu* xB = xA + (size_t)BATCH * Rrows * 64;

    const int totw = (int)(WCAT_E + WRB_E);
    prep_weights<<<(totw + 255) / 256, 256, 0, stream>>>(Wd, Wr, wcat, wrb);

    bfu* bufs[2] = {xA, xB};
    for (long s = 0; s < FINLEN; s += CH) {
        long CHc  = (FINLEN - s < CH) ? (FINLEN - s) : CH;   // multiple of 256
        int  len0 = (int)(CHc + RFIELD);

        int cur = 0;
        int L = len0;
        for (int i = 0; i < NLAYERS; ++i) {
            int d = 1 << (i & 7);
            int Lout = L - d;
            int tiles = (Lout + T_TILE - 1) / T_TILE;
            // grid cap: 40KB LDS -> 4 blocks/CU -> 1024 resident slots; bx <= 128
            int NT    = (tiles + 127) / 128;
            int bx    = (tiles + NT - 1) / NT;
            dim3 grid(bx, BATCH);
            const bfu* xi = bufs[cur];
            bfu*       xo = bufs[cur ^ 1];
            const bfu* wc  = wcat + (size_t)i * 128 * 128;
            const bfu* wr2 = wrb  + (size_t)i * 64 * 128;
            const float* bdl = bd + i * 128;
            const float* brl = br + i * 64;
            if (i == 0)
                layer_kernel<1><<<grid, 256, 0, stream>>>(xi, xo, wc, wr2, bdl, brl,
                    sig, W0, b0, Wf, partial, (int)s, d, L, Lout, (int)Rrows, NT, tiles);
            else if (i == NLAYERS - 1)
                layer_kernel<2><<<grid, 256, 0, stream>>>(xi, xo, wc, wr2, bdl, brl,
                    sig, W0, b0, Wf, partial, (int)s, d, L, Lout, (int)Rrows, NT, tiles);
            else
                layer_kernel<0><<<grid, 256, 0, stream>>>(xi, xo, wc, wr2, bdl, brl,
                    sig, W0, b0, Wf, partial, (int)s, d, L, Lout, (int)Rrows, NT, tiles);
            cur ^= 1;
            L = Lout;
        }
    }
    pool_reduce<<<(BATCH * 510 + 255) / 256, 256, 0, stream>>>(partial, bf, out);
}

// Round 22
// 1460.449 us; speedup vs baseline: 1.0161x; 1.0161x over previous
//
#include <hip/hip_runtime.h>
#include <hip/hip_bf16.h>
#include <stdint.h>

typedef __attribute__((ext_vector_type(8))) short short8;
typedef __attribute__((ext_vector_type(4))) float f32x4;
typedef unsigned short bfu;

#define T_TILE  64
#define RING    256            // ring rows (pow2): live span/tile = 128+d <= 256 for d<=128
#define NLAYERS 16
#define T0LEN   131072
#define BATCH   8
#define RFIELD  510            // sum of dilations
#define FINLEN  130560         // 510 pool windows * 256
#define CHCAP   65280          // chunk cap: 2x bf16 buffers (~135MB) stay L3-resident

// barrier WITHOUT vmcnt drain: safe (no cross-wave GLOBAL communication inside
// a layer kernel; only LDS visibility needed). Global loads stay in flight.
#define BARRIER() asm volatile("s_waitcnt lgkmcnt(0)\n\ts_barrier" ::: "memory")

__device__ __forceinline__ bfu f2bf(float f) {
    unsigned u = __float_as_uint(f);
    u += 0x7FFFu + ((u >> 16) & 1u);      // RNE (cold prep kernel only)
    return (bfu)(u >> 16);
}
__device__ __forceinline__ unsigned pk2(float a, float b) {
    __hip_bfloat16 lo = __float2bfloat16(a);
    __hip_bfloat16 hi = __float2bfloat16(b);
    unsigned short ul = __builtin_bit_cast(unsigned short, lo);
    unsigned short uh = __builtin_bit_cast(unsigned short, hi);
    return (unsigned)ul | ((unsigned)uh << 16);
}
__device__ __forceinline__ float bf2f(bfu h) { return __uint_as_float(((unsigned)h) << 16); }
__device__ __forceinline__ unsigned relu2(unsigned w) {
    return w & ~(((w >> 15) & 0x00010001u) * 0xFFFFu);
}

// ---- weights: Wd[l][o][c][tap] -> wcat[l][o][k] bf16 (k=tap*64+c); Wr -> wrb bf16
__global__ void prep_weights(const float* __restrict__ Wd, const float* __restrict__ Wr,
                             bfu* __restrict__ wcat, bfu* __restrict__ wrb)
{
    int idx = blockIdx.x * 256 + threadIdx.x;
    const int total1 = NLAYERS * 128 * 128;
    if (idx < total1) {
        int k = idx & 127, o = (idx >> 7) & 127, l = idx >> 14;
        int tap = k >> 6, c = k & 63;
        wcat[idx] = f2bf(Wd[(((l * 128 + o) * 64) + c) * 2 + tap]);
    } else {
        int j = idx - total1;
        if (j < NLAYERS * 64 * 128) wrb[j] = f2bf(Wr[j]);
    }
}

// MODE: 0 = middle, 1 = first (input conv fused; d==1), 2 = last (final conv+pool fused)
// T_TILE=64: ring 256 rows (32KB) + hb 64x128 (16KB) = 48KB -> 3 blocks/CU.
// BEST MEASURED CONFIG (r20: 1471us): tile sweep T128@2blk=71us, T64@3blk=60us,
// T32@4blk=63us per dispatch -> optimum here. Ring reuse, 2 lgkm barriers/tile,
// reg-staged prefetch, pk2 epilogues, bias-in-accumulator, setprio on MFMA.
template <int MODE>
__global__ __launch_bounds__(256, 3)
void layer_kernel(const bfu* __restrict__ xin, bfu* __restrict__ xout,
                  const bfu* __restrict__ wcat, const bfu* __restrict__ wrb,
                  const float* __restrict__ bd, const float* __restrict__ br,
                  const float* __restrict__ sig, const float* __restrict__ W0,
                  const float* __restrict__ b0, const float* __restrict__ Wf,
                  float* __restrict__ partial,
                  int s, int d, int Lin, int Lout, int Rrows, int NT, int tiles)
{
    __shared__ bfu rx[RING * 64];      // 32 KB ring: relu(x) bf16, swizzled rows
    __shared__ bfu hb[64 * 128];       // 16 KB: relu(h+bd) bf16, swizzled

    const int tid  = threadIdx.x;
    const int lane = tid & 63;
    const int wv   = tid >> 6;
    const int l15  = lane & 15;
    const int lg   = lane >> 4;
    const int b    = blockIdx.y;

    const bfu* xb = xin  + (long)b * Rrows * 64;
    bfu*       xo = xout + (long)b * Rrows * 64;
    const float* sgb = sig + (long)b * T0LEN + s;

    // ---- loop-invariant: weight A-fragments, biases ----
    short8 a1[2][4];
    #pragma unroll
    for (int m = 0; m < 2; ++m)
        #pragma unroll
        for (int k = 0; k < 4; ++k)
            a1[m][k] = *(const short8*)(wcat + ((wv * 32 + m * 16 + l15) << 7) + (k << 5) + (lg << 3));
    short8 a2[4];
    #pragma unroll
    for (int k = 0; k < 4; ++k)
        a2[k] = *(const short8*)(wrb + ((wv * 16 + l15) << 7) + (k << 5) + (lg << 3));

    const int c0 = wv * 16 + lg * 4;
    const f32x4 brv = *(const f32x4*)(br + c0);
    f32x4 bd4[2];
    #pragma unroll
    for (int m = 0; m < 2; ++m)
        bd4[m] = *(const f32x4*)(bd + wv * 32 + m * 16 + lg * 4);
    f32x4 wfv;
    if constexpr (MODE == 2) wfv = *(const f32x4*)(Wf + c0);

    const int tile0 = blockIdx.x * NT;
    const int jmax  = (tiles - tile0 < NT) ? (tiles - tile0) : NT;
    if (jmax <= 0) return;
    const int t00   = tile0 * T_TILE;

    // ---- prologue: stage rows [t00, t00+T_TILE+d) into ring ----
    if constexpr (MODE == 1) {
        const int nsl = (T_TILE + 1) * 8;            // d == 1 -> 520
        #pragma unroll
        for (int it = 0; it < 3; ++it) {
            int i = tid + it * 256;
            if (i < nsl) {
                int r = i >> 3, oc = i & 7;
                int t = t00 + r; if (t > Lin - 1) t = Lin - 1;
                float sv = sgb[t];
                unsigned pk[4];
                #pragma unroll
                for (int kk = 0; kk < 4; ++kk) {
                    int c = oc * 8 + kk * 2;
                    pk[kk] = pk2(fmaxf(W0[c] * sv + b0[c], 0.f),
                                 fmaxf(W0[c + 1] * sv + b0[c + 1], 0.f));
                }
                int rs = (t00 + r) & (RING - 1);
                uint4 u; u.x = pk[0]; u.y = pk[1]; u.z = pk[2]; u.w = pk[3];
                *(uint4*)&rx[(rs << 6) + ((oc ^ (rs & 7)) << 3)] = u;
            }
        }
    } else {
        const int nsl = (T_TILE + d) * 8;            // <= 1536
        uint4 pv[6];
        #pragma unroll
        for (int it = 0; it < 6; ++it) {             // batch-issue all loads
            int i = tid + it * 256;
            if (i < nsl) {
                int r = i >> 3, oc = i & 7;
                long t = t00 + r; if (t > Lin - 1) t = Lin - 1;
                pv[it] = *(const uint4*)(xb + t * 64 + oc * 8);
            }
        }
        #pragma unroll
        for (int it = 0; it < 6; ++it) {             // then all writes
            int i = tid + it * 256;
            if (i < nsl) {
                int r = i >> 3, oc = i & 7;
                int rs = (t00 + r) & (RING - 1);
                uint4 v = pv[it];
                v.x = relu2(v.x); v.y = relu2(v.y); v.z = relu2(v.z); v.w = relu2(v.w);
                *(uint4*)&rx[(rs << 6) + ((oc ^ (rs & 7)) << 3)] = v;
            }
        }
    }

    for (int j = 0; j < jmax; ++j) {
        const int t0    = t00 + j * T_TILE;
        const int base0 = t0 & (RING - 1);
        const int rbase = t0 + T_TILE + d;           // first new row for tile j+1

        BARRIER();   // top: all waves done with prev GEMM2 (hb free); ring stage visible

        // ---- issue prefetch of tile j+1's 64 new rows (in flight through GEMM1) ----
        // no-wrap proof: live span = [t0, rbase+63] = 128+d <= 256 = RING; prefetch
        // slots (t0+64+d .. t0+127+d) are disjoint from reader rows (t0 .. t0+63+d).
        uint4 pf[2];
        float pfs[2];
        const bool havePF = (j + 1 < jmax);
        if (havePF) {
            if constexpr (MODE == 1) {
                #pragma unroll
                for (int it = 0; it < 2; ++it) {
                    int i = tid + it * 256;
                    int t = rbase + (i >> 3); if (t > Lin - 1) t = Lin - 1;
                    pfs[it] = sgb[t];
                }
            } else {
                #pragma unroll
                for (int it = 0; it < 2; ++it) {
                    int i = tid + it * 256;
                    int oc = i & 7;
                    long t = rbase + (i >> 3); if (t > Lin - 1) t = Lin - 1;
                    pf[it] = *(const uint4*)(xb + t * 64 + oc * 8);
                }
            }
        }

        // ---- issue skip loads for this tile (consumed at epilogue 2) ----
        uint2 sk[4];
        float skv[4];
        if constexpr (MODE == 1) {
            #pragma unroll
            for (int n = 0; n < 4; ++n) {
                int t = t0 + n * 16 + l15;
                skv[n] = (t < Lout) ? sgb[t + d] : 0.f;
            }
        } else {
            #pragma unroll
            for (int n = 0; n < 4; ++n) {
                int t = t0 + n * 16 + l15;
                uint2 z = {0u, 0u};
                sk[n] = (t < Lout) ? *(const uint2*)(xb + (long)(t + d) * 64 + c0) : z;
            }
        }

        // ---- GEMM1: H[o][t] = bd[o] + sum_k Wcat[o][k] * RX[k][t] ----
        f32x4 acc[2][4];
        #pragma unroll
        for (int m = 0; m < 2; ++m)
            #pragma unroll
            for (int n = 0; n < 4; ++n) acc[m][n] = bd4[m];
        __builtin_amdgcn_s_setprio(1);
        #pragma unroll
        for (int k = 0; k < 4; ++k) {
            const int roff = (k >> 1) ? d : 0;
            const int g    = ((k & 1) << 2) + lg;
            #pragma unroll
            for (int n = 0; n < 4; ++n) {
                int rr = (base0 + n * 16 + l15 + roff) & (RING - 1);
                short8 bv = *(const short8*)&rx[(rr << 6) + ((g ^ (rr & 7)) << 3)];
                acc[0][n] = __builtin_amdgcn_mfma_f32_16x16x32_bf16(a1[0][k], bv, acc[0][n], 0, 0, 0);
                acc[1][n] = __builtin_amdgcn_mfma_f32_16x16x32_bf16(a1[1][k], bv, acc[1][n], 0, 0, 0);
            }
        }
        __builtin_amdgcn_s_setprio(0);

        // ---- epilogue 1: relu, bf16 -> hb swizzled ----
        #pragma unroll
        for (int m = 0; m < 2; ++m) {
            const int o0 = wv * 32 + m * 16 + lg * 4;
            const int gg = o0 >> 3;
            #pragma unroll
            for (int n = 0; n < 4; ++n) {
                int t = n * 16 + l15;
                f32x4 h = acc[m][n];
                unsigned q01 = pk2(fmaxf(h.x, 0.f), fmaxf(h.y, 0.f));
                unsigned q23 = pk2(fmaxf(h.z, 0.f), fmaxf(h.w, 0.f));
                int idx = (t << 7) + (((gg ^ (t & 15)) << 3) | (o0 & 7));
                uint2 pk; pk.x = q01; pk.y = q23;
                *(uint2*)&hb[idx] = pk;
            }
        }

        // ---- write prefetched rows into ring (slots disjoint from tile j readers) ----
        if (havePF) {
            if constexpr (MODE == 1) {
                #pragma unroll
                for (int it = 0; it < 2; ++it) {
                    int i = tid + it * 256;
                    int r = i >> 3, oc = i & 7;
                    float sv = pfs[it];
                    unsigned pk[4];
                    #pragma unroll
                    for (int kk = 0; kk < 4; ++kk) {
                        int c = oc * 8 + kk * 2;
                        pk[kk] = pk2(fmaxf(W0[c] * sv + b0[c], 0.f),
                                     fmaxf(W0[c + 1] * sv + b0[c + 1], 0.f));
                    }
                    int rs = (rbase + r) & (RING - 1);
                    uint4 u; u.x = pk[0]; u.y = pk[1]; u.z = pk[2]; u.w = pk[3];
                    *(uint4*)&rx[(rs << 6) + ((oc ^ (rs & 7)) << 3)] = u;
                }
            } else {
                #pragma unroll
                for (int it = 0; it < 2; ++it) {
                    int i = tid + it * 256;
                    int r = i >> 3, oc = i & 7;
                    int rs = (rbase + r) & (RING - 1);
                    uint4 v = pf[it];
                    v.x = relu2(v.x); v.y = relu2(v.y); v.z = relu2(v.z); v.w = relu2(v.w);
                    *(uint4*)&rx[(rs << 6) + ((oc ^ (rs & 7)) << 3)] = v;
                }
            }
        }

        BARRIER();   // mid: hb visible; ring writes drained for next top-barrier

        // ---- GEMM2: Y[r][t] = br[r] + sum_o Wr[r][o] * Hb[o][t] ----
        f32x4 acc2[4];
        #pragma unroll
        for (int n = 0; n < 4; ++n) acc2[n] = brv;
        __builtin_amdgcn_s_setprio(1);
        #pragma unroll
        for (int k = 0; k < 4; ++k) {
            const int g = (k << 2) + lg;
            #pragma unroll
            for (int n = 0; n < 4; ++n) {
                int t = n * 16 + l15;
                short8 bfm = *(const short8*)&hb[(t << 7) + ((g ^ (t & 15)) << 3)];
                acc2[n] = __builtin_amdgcn_mfma_f32_16x16x32_bf16(a2[k], bfm, acc2[n], 0, 0, 0);
            }
        }
        __builtin_amdgcn_s_setprio(0);

        // ---- epilogue 2: +skip; store bf16 or fused Wf-dot partial ----
        float psum = 0.f;
        #pragma unroll
        for (int n = 0; n < 4; ++n) {
            int t = t0 + n * 16 + l15;
            if (t < Lout) {
                float s0, s1, s2, s3;
                if constexpr (MODE == 1) {
                    float sv = skv[n];
                    s0 = W0[c0] * sv + b0[c0];         s1 = W0[c0 + 1] * sv + b0[c0 + 1];
                    s2 = W0[c0 + 2] * sv + b0[c0 + 2]; s3 = W0[c0 + 3] * sv + b0[c0 + 3];
                } else {
                    s0 = bf2f((bfu)(sk[n].x & 0xFFFF)); s1 = bf2f((bfu)(sk[n].x >> 16));
                    s2 = bf2f((bfu)(sk[n].y & 0xFFFF)); s3 = bf2f((bfu)(sk[n].y >> 16));
                }
                float y0 = acc2[n].x + s0;
                float y1 = acc2[n].y + s1;
                float y2 = acc2[n].z + s2;
                float y3 = acc2[n].w + s3;
                if constexpr (MODE == 2) {
                    psum += wfv.x * y0 + wfv.y * y1 + wfv.z * y2 + wfv.w * y3;
                } else {
                    uint2 pk;
                    pk.x = pk2(y0, y1);
                    pk.y = pk2(y2, y3);
                    *(uint2*)(xo + (long)t * 64 + c0) = pk;
                }
            }
        }
        if constexpr (MODE == 2) {
            #pragma unroll
            for (int off = 32; off > 0; off >>= 1) psum += __shfl_down(psum, off, 64);
            if (lane == 0)
                partial[((long)b * 2048 + ((s + t0) >> 6)) * 4 + wv] = psum;   // per-64-tile
        }
    }
}

// ---- final: out[b][w] = (sum of 16 partials: 4 tiles x 4 waves)/256 + bf ----
__global__ void pool_reduce(const float* __restrict__ part, const float* __restrict__ bfp,
                            float* __restrict__ out)
{
    int i = blockIdx.x * 256 + threadIdx.x;
    if (i >= BATCH * 510) return;
    int b = i / 510, w = i % 510;
    const float* p = part + ((long)b * 2048 + 4 * w) * 4;
    float sum = 0.f;
    #pragma unroll
    for (int q = 0; q < 16; ++q) sum += p[q];
    out[i] = sum * (1.0f / 256.0f) + bfp[0];
}

extern "C" void kernel_launch(void* const* d_in, const int* in_sizes, int n_in,
                              void* d_out, int out_size, void* d_ws, size_t ws_size,
                              hipStream_t stream) {
    const float* sig = (const float*)d_in[0];
    const float* W0  = (const float*)d_in[1];
    const float* b0  = (const float*)d_in[2];
    const float* Wd  = (const float*)d_in[3];
    const float* bd  = (const float*)d_in[4];
    const float* Wr  = (const float*)d_in[5];
    const float* br  = (const float*)d_in[6];
    const float* Wf  = (const float*)d_in[7];
    const float* bf  = (const float*)d_in[8];
    float* out = (float*)d_out;

    // ---- workspace: [wcat | wrb | partial | xA | xB] ----
    char* ws = (char*)d_ws;
    const size_t WCAT_E = (size_t)NLAYERS * 128 * 128;
    const size_t WRB_E  = (size_t)NLAYERS * 64 * 128;
    const size_t WBYTES = (WCAT_E + WRB_E) * 2;          // 786432
    const size_t PARTB  = (size_t)BATCH * 2048 * 4 * 4;  // 262144
    bfu*   wcat    = (bfu*)ws;
    bfu*   wrb     = (bfu*)(ws + WCAT_E * 2);
    float* partial = (float*)(ws + WBYTES);

    if (ws_size < WBYTES + PARTB + (size_t)2 * BATCH * 766 * 64 * 2) return;

    size_t avail   = ws_size - WBYTES - PARTB;
    long   rowsMax = (long)(avail / ((size_t)2 * BATCH * 64 * 2));
    long   CH      = ((rowsMax - RFIELD) / 256) * 256;
    if (CH > CHCAP) CH = CHCAP;        // L3 blocking
    if (CH < 256)   CH = 256;
    const long Rrows = CH + RFIELD;

    bfu* xA = (bfu*)(ws + WBYTES + PARTB);
    bfu* xB = xA + (size_t)BATCH * Rrows * 64;

    const int totw = (int)(WCAT_E + WRB_E);
    prep_weights<<<(totw + 255) / 256, 256, 0, stream>>>(Wd, Wr, wcat, wrb);

    bfu* bufs[2] = {xA, xB};
    for (long s = 0; s < FINLEN; s += CH) {
        long CHc  = (FINLEN - s < CH) ? (FINLEN - s) : CH;   // multiple of 256
        int  len0 = (int)(CHc + RFIELD);

        int cur = 0;
        int L = len0;
        for (int i = 0; i < NLAYERS; ++i) {
            int d = 1 << (i & 7);
            int Lout = L - d;
            int tiles = (Lout + T_TILE - 1) / T_TILE;
            // grid cap: 48KB LDS -> 3 blocks/CU -> 768 resident slots; bx <= 96
            int NT    = (tiles + 95) / 96;
            int bx    = (tiles + NT - 1) / NT;
            dim3 grid(bx, BATCH);
            const bfu* xi = bufs[cur];
            bfu*       xo = bufs[cur ^ 1];
            const bfu* wc  = wcat + (size_t)i * 128 * 128;
            const bfu* wr2 = wrb  + (size_t)i * 64 * 128;
            const float* bdl = bd + i * 128;
            const float* brl = br + i * 64;
            if (i == 0)
                layer_kernel<1><<<grid, 256, 0, stream>>>(xi, xo, wc, wr2, bdl, brl,
                    sig, W0, b0, Wf, partial, (int)s, d, L, Lout, (int)Rrows, NT, tiles);
            else if (i == NLAYERS - 1)
                layer_kernel<2><<<grid, 256, 0, stream>>>(xi, xo, wc, wr2, bdl, brl,
                    sig, W0, b0, Wf, partial, (int)s, d, L, Lout, (int)Rrows, NT, tiles);
            else
                layer_kernel<0><<<grid, 256, 0, stream>>>(xi, xo, wc, wr2, bdl, brl,
                    sig, W0, b0, Wf, partial, (int)s, d, L, Lout, (int)Rrows, NT, tiles);
            cur ^= 1;
            L = Lout;
        }
    }
    pool_reduce<<<(BATCH * 510 + 255) / 256, 256, 0, stream>>>(partial, bf, out);
}